// Round 4
// baseline (267.621 us; speedup 1.0000x reference)
//
#include <hip/hip_runtime.h>

// QuadraticBaseMorpho: out[h][w] = max_{dy,dx in [-3,3]} xpad[h+dy][w+dx] + nb[dy+3][dx+3]
// xpad = x padded with -10000. nb = -(se/se.max()) with center forced to -10000.
// se is even-symmetric -> the [::-1,::-1] flip is identity.
// Input (8,64,256,256) fp32 = 512 planes of 256x256.
//
// Round-4 experiment: explicit in-wave ILP. Round 3 (no-LDS) compiled to
// VGPR=32 under launch_bounds(256,8): zero loads in flight, every row was
// load -> vmcnt(0) -> consume. All structures so far (barriers or raw loads)
// exposed memory latency; no pipe is saturated. Here the row loads are
// software-pipelined through a 5-slot register ring with depth-4 prefetch:
// at step iy issue row iy+4 (3 vf4 loads) into slot (iy+4)%5, consume row iy
// from slot iy%5. rows/chunk = 10 == 0 mod 5 -> ring phase identical across
// chunks: single runtime k loop, all slot indices compile-time. Cross-chunk
// prefetch falls out (rows 0..3 of chunk k+1 issue during iy 6..9 of chunk
// k). Steady state: 12 loads in flight/wave, ~700 cycles of compute cover
// per row vs ~400-700 cy L2/L3-hit latency. launch_bounds(256,4): ~105 VGPR,
// 16 waves/CU -> ~190 outstanding loads/CU.
//
// Inner math unchanged from rounds 1-3 (validated absmax=0): per (t,c)
// 3 v_pk_add_f32 + 1 add + 3 v_max3 + 1 max. Pad rows skipped entirely
// (-MAXV+w can never beat a real candidate; dy=0 always real).

#define MAXV 10000.0f

constexpr int H = 256;
constexpr int W = 256;

typedef float vf4 __attribute__((ext_vector_type(4)));
typedef float vf2 __attribute__((ext_vector_type(2)));

__global__ __launch_bounds__(256, 4) void morpho_kernel(
    const float* __restrict__ x,
    const float* __restrict__ k1p,
    const float* __restrict__ k2p,
    const float* __restrict__ k3p,
    float* __restrict__ out) {
  const int tid = threadIdx.x;
  const int lane = tid & 63;
  const int wid = __builtin_amdgcn_readfirstlane(tid >> 6);  // wave id, uniform
  const int p = blockIdx.x >> 2;                 // plane (512)
  const int ty0 = (blockIdx.x & 3) * 64;         // block's first output row

  const float* __restrict__ xp = x + (size_t)p * (H * W);
  float* __restrict__ op = out + (size_t)p * (H * W);

  // ---- SE: one weight per lane (8x8 grid), shuffle-max, readlane -> SGPRs ----
  const float k1v = k1p[0], k2v = k2p[0], k3v = k3p[0];
  const int ia = lane >> 3, ib = lane & 7;
  const float xg = (float)(((ib < 6) ? ib : 6) - 3);   // clamp dup lanes; max unaffected
  const float yg = (float)(((ia < 6) ? ia : 6) - 3);
  const float sev = k1v * (xg * xg) + 2.0f * k2v * (xg * yg) + k3v * (yg * yg);
  float mx = sev;
#pragma unroll
  for (int off = 32; off; off >>= 1) mx = fmaxf(mx, __shfl_xor(mx, off, 64));
  const float wv = 0.0f - sev * (1.0f / mx);

  // weight row d: pairs (w0,w1)(w2,w3)(w4,w5) + scalar w6 -> 49 SGPRs total
  vf2 wp[7][3];
  float w6[7];
#pragma unroll
  for (int d = 0; d < 7; ++d) {
#pragma unroll
    for (int m = 0; m < 3; ++m) {
      vf2 pr;
      pr.x = __int_as_float(__builtin_amdgcn_readlane(__float_as_int(wv), d * 8 + 2 * m));
      pr.y = __int_as_float(__builtin_amdgcn_readlane(__float_as_int(wv), d * 8 + 2 * m + 1));
      wp[d][m] = pr;
    }
    w6[d] = __int_as_float(__builtin_amdgcn_readlane(__float_as_int(wv), d * 8 + 6));
  }
  wp[3][1].y = -MAXV;                            // masked center (d=3, j=3)

  // ---- per-lane load offsets (float indices), clamped into the row ----
  const bool l0 = (lane == 0);
  const bool l63 = (lane == 63);
  const int o1 = lane * 4;                       // q1: cols lane*4 .. +3
  const int o0 = l0 ? o1 : o1 - 4;               // q0: cols lane*4-4 .. -1
  const int o2 = l63 ? o1 : o1 + 4;              // q2: cols lane*4+4 .. +7

  const int y00 = ty0 + 4 * wid;                 // chunk k base = y00 + 16k

  // ---- 5-slot register ring, depth-4 prefetch ----
  vf4 st[5][3];

  // prologue: logical rows q=0..3 (input rows y00-3 .. y00) -> slots 0..3
#pragma unroll
  for (int q = 0; q < 4; ++q) {
    const int r = y00 - 3 + q;                   // < H always; only r<0 clamps
    if (r >= 0) {
      const float* __restrict__ rb = xp + r * W;
      st[q][0] = *reinterpret_cast<const vf4*>(rb + o0);
      st[q][1] = *reinterpret_cast<const vf4*>(rb + o1);
      st[q][2] = *reinterpret_cast<const vf4*>(rb + o2);
    }
  }

  for (int k = 0; k < 4; ++k) {
    const int y0c = y00 + 16 * k;                // chunk base output row

    float acc[4][4];
#pragma unroll
    for (int t = 0; t < 4; ++t)
#pragma unroll
      for (int c = 0; c < 4; ++c) acc[t][c] = -INFINITY;

#pragma unroll
    for (int iy = 0; iy < 10; ++iy) {
      // ---- issue logical row q+4 into slot (iy+4)%5 (compile-time) ----
      {
        const int slot = (iy + 4) % 5;
        // same chunk for iy<6 (row y0c+1+iy), next chunk for iy>=6 (row y0c+7+iy)
        const int r2 = (iy < 6) ? (y0c + 1 + iy) : (y0c + 7 + iy);
        if (r2 < H && (iy < 6 || k < 3)) {       // wave-uniform guard
          const float* __restrict__ rb = xp + r2 * W;
          st[slot][0] = *reinterpret_cast<const vf4*>(rb + o0);
          st[slot][1] = *reinterpret_cast<const vf4*>(rb + o1);
          st[slot][2] = *reinterpret_cast<const vf4*>(rb + o2);
        }
      }

      // ---- consume row iy (input row y0c-3+iy) from slot iy%5 ----
      const int r = y0c - 3 + iy;
      if (r < 0 || r >= H) continue;             // wave-uniform; pad rows skipped
      const int cs = iy % 5;

      vf4 q0 = st[cs][0];                        // buf[0..3]
      vf4 q1 = st[cs][1];                        // buf[4..7]
      vf4 q2 = st[cs][2];                        // buf[8..11]

      // edge fixes: lane 0's cols -3..-1, lane 63's cols 256..258 -> -MAXV
      q0.y = l0 ? -MAXV : q0.y;
      q0.z = l0 ? -MAXV : q0.z;
      q0.w = l0 ? -MAXV : q0.w;
      q2.x = l63 ? -MAXV : q2.x;
      q2.y = l63 ? -MAXV : q2.y;
      q2.z = l63 ? -MAXV : q2.z;

      // odd-start pairs (2 movs each): (b1,b2)(b3,b4)(b5,b6)(b7,b8)
      const vf2 O0 = __builtin_shufflevector(q0, q0, 1, 2);
      const vf2 O1 = __builtin_shufflevector(q0, q1, 3, 4);
      const vf2 O2 = __builtin_shufflevector(q1, q1, 1, 2);
      const vf2 O3 = __builtin_shufflevector(q1, q2, 3, 4);
      // even-start pairs (free quad sub-pairs): (b2,b3)(b4,b5)(b6,b7)(b8,b9)
      const vf2 E0 = __builtin_shufflevector(q0, q0, 2, 3);
      const vf2 E1 = __builtin_shufflevector(q1, q1, 0, 1);
      const vf2 E2 = __builtin_shufflevector(q1, q1, 2, 3);
      const vf2 E3 = __builtin_shufflevector(q2, q2, 0, 1);

      const vf2 P[4][3] = {{O0, O1, O2}, {E0, E1, E2}, {O1, O2, O3}, {E1, E2, E3}};
      const float T[4] = {q1.w, q2.x, q2.y, q2.z};

#pragma unroll
      for (int t = 0; t < 4; ++t) {
        const int dyr = iy - t;                  // nb row index = dy+3
        if (dyr < 0 || dyr > 6) continue;        // dead after unroll
#pragma unroll
        for (int c = 0; c < 4; ++c) {
          const vf2 a = P[c][0] + wp[dyr][0];    // v_pk_add_f32
          const vf2 b = P[c][1] + wp[dyr][1];    // v_pk_add_f32
          const vf2 g = P[c][2] + wp[dyr][2];    // v_pk_add_f32
          const float s6 = T[c] + w6[dyr];
          const float m0 = fmaxf(fmaxf(a.x, a.y), b.x);   // v_max3
          const float m1 = fmaxf(fmaxf(b.y, g.x), g.y);   // v_max3
          const float m2 = fmaxf(fmaxf(s6, m0), m1);      // v_max3
          acc[t][c] = fmaxf(acc[t][c], m2);
        }
      }
    }

    // store chunk (nontemporal: output is never re-read; keep caches for x)
#pragma unroll
    for (int t = 0; t < 4; ++t) {
      vf4 v;
      v.x = acc[t][0];
      v.y = acc[t][1];
      v.z = acc[t][2];
      v.w = acc[t][3];
      __builtin_nontemporal_store(
          v, reinterpret_cast<vf4*>(&op[(y0c + t) * W + lane * 4]));
    }
  }
}

extern "C" void kernel_launch(void* const* d_in, const int* in_sizes, int n_in,
                              void* d_out, int out_size, void* d_ws, size_t ws_size,
                              hipStream_t stream) {
  const float* x = (const float*)d_in[0];
  const float* k1 = (const float*)d_in[1];
  const float* k2 = (const float*)d_in[2];
  const float* k3 = (const float*)d_in[3];
  float* outp = (float*)d_out;

  const int planes = 8 * 64;                     // 512
  const int blocks = planes * 4;                 // 2048 (64 rows per block)
  morpho_kernel<<<dim3(blocks), dim3(256), 0, stream>>>(x, k1, k2, k3, outp);
}

// Round 5
// 249.418 us; speedup vs baseline: 1.0730x; 1.0730x over previous
//
#include <hip/hip_runtime.h>

// QuadraticBaseMorpho: out[h][w] = max_{dy,dx in [-3,3]} xpad[h+dy][w+dx] + nb[dy+3][dx+3]
// xpad = x padded with -10000. nb = -(se/se.max()) with center forced to -10000.
// se is even-symmetric -> the [::-1,::-1] flip is identity.
// Input (8,64,256,256) fp32 = 512 planes of 256x256.
//
// Round-5: streaming sliding-window. Each wave owns 16 CONTIGUOUS output rows
// and streams its 22 input rows exactly once (66 loads/wave vs 120 in the
// chunked r3/r4 mapping). Arriving row r contributes to all live outputs
// (up to 7 weight-rows at once) then dies; accumulators rotate through 7
// slots (t%7): each step stores one finished output row and re-inits the
// slot for the incoming one. Prefetch: 3-slot register ring, depth-2,
// UNCONDITIONAL loads with clamped row addresses (r4 post-mortem: VGPR=52
// proved guarded prefetch collapses the pipeline; clamped-address loads have
// no branches so the compiler keeps them in flight; clamped garbage is never
// consumed because pad steps are skipped, and the skip branch only survives
// at compile-time edge iys). All %3/%7 slot indices are compile-time (full
// 22-step unroll, rule: no runtime-indexed ext_vector arrays).
//
// Inner math unchanged from rounds 1-4 (validated absmax=0): per (t,c,d)
// 3 v_pk_add_f32 + 1 add + 3 v_max3 + 1 max. Pad rows skipped (-MAXV+w can
// never beat a real candidate; dy=0 always real).

#define MAXV 10000.0f

constexpr int H = 256;
constexpr int W = 256;

typedef float vf4 __attribute__((ext_vector_type(4)));
typedef float vf2 __attribute__((ext_vector_type(2)));

__global__ __launch_bounds__(256, 4) void morpho_kernel(
    const float* __restrict__ x,
    const float* __restrict__ k1p,
    const float* __restrict__ k2p,
    const float* __restrict__ k3p,
    float* __restrict__ out) {
  const int tid = threadIdx.x;
  const int lane = tid & 63;
  const int wid = __builtin_amdgcn_readfirstlane(tid >> 6);  // wave id, uniform
  const int p = blockIdx.x >> 2;                 // plane (512)
  const int y0w = (blockIdx.x & 3) * 64 + wid * 16;  // wave's first output row

  const float* __restrict__ xp = x + (size_t)p * (H * W);
  float* __restrict__ op = out + (size_t)p * (H * W);

  // ---- SE: one weight per lane (8x8 grid), shuffle-max, readlane -> SGPRs ----
  const float k1v = k1p[0], k2v = k2p[0], k3v = k3p[0];
  const int ia = lane >> 3, ib = lane & 7;
  const float xg = (float)(((ib < 6) ? ib : 6) - 3);   // clamp dup lanes; max unaffected
  const float yg = (float)(((ia < 6) ? ia : 6) - 3);
  const float sev = k1v * (xg * xg) + 2.0f * k2v * (xg * yg) + k3v * (yg * yg);
  float mx = sev;
#pragma unroll
  for (int off = 32; off; off >>= 1) mx = fmaxf(mx, __shfl_xor(mx, off, 64));
  const float wv = 0.0f - sev * (1.0f / mx);

  // weight row d: pairs (w0,w1)(w2,w3)(w4,w5) + scalar w6 -> 49 SGPRs total
  vf2 wp[7][3];
  float w6[7];
#pragma unroll
  for (int d = 0; d < 7; ++d) {
#pragma unroll
    for (int m = 0; m < 3; ++m) {
      vf2 pr;
      pr.x = __int_as_float(__builtin_amdgcn_readlane(__float_as_int(wv), d * 8 + 2 * m));
      pr.y = __int_as_float(__builtin_amdgcn_readlane(__float_as_int(wv), d * 8 + 2 * m + 1));
      wp[d][m] = pr;
    }
    w6[d] = __int_as_float(__builtin_amdgcn_readlane(__float_as_int(wv), d * 8 + 6));
  }
  wp[3][1].y = -MAXV;                            // masked center (d=3, j=3)

  // ---- per-lane load offsets (float indices), clamped into the row ----
  const bool l0 = (lane == 0);
  const bool l63 = (lane == 63);
  const int o1 = lane * 4;                       // q1: cols lane*4 .. +3
  const int o0 = l0 ? o1 : o1 - 4;               // q0: cols lane*4-4 .. -1
  const int o2 = l63 ? o1 : o1 + 4;              // q2: cols lane*4+4 .. +7

  // ---- 3-slot prefetch ring (depth 2), unconditional clamped loads ----
  vf4 ring[3][3];
  {
    const int r0 = (y0w - 3 < 0) ? 0 : y0w - 3;  // iy=0 (<= 237 always)
    const float* __restrict__ rb = xp + r0 * W;
    ring[0][0] = *reinterpret_cast<const vf4*>(rb + o0);
    ring[0][1] = *reinterpret_cast<const vf4*>(rb + o1);
    ring[0][2] = *reinterpret_cast<const vf4*>(rb + o2);
  }
  {
    const int r1 = (y0w - 2 < 0) ? 0 : y0w - 2;  // iy=1
    const float* __restrict__ rb = xp + r1 * W;
    ring[1][0] = *reinterpret_cast<const vf4*>(rb + o0);
    ring[1][1] = *reinterpret_cast<const vf4*>(rb + o1);
    ring[1][2] = *reinterpret_cast<const vf4*>(rb + o2);
  }

  // ---- 7 rotating accumulator slots (slot = t % 7) ----
  float acc[7][4];
#pragma unroll
  for (int s = 0; s < 7; ++s)
#pragma unroll
    for (int c = 0; c < 4; ++c) acc[s][c] = -INFINITY;

#pragma unroll
  for (int iy = 0; iy < 22; ++iy) {              // input rows y0w-3 .. y0w+18
    // ---- prefetch row for step iy+2 into slot (iy+2)%3 (no guards!) ----
    if (iy < 20) {                               // compile-time
      int rp = y0w - 1 + iy;                     // = y0w-3+(iy+2)
      rp = (rp < 0) ? 0 : ((rp > H - 1) ? H - 1 : rp);   // clamp, branchless
      const float* __restrict__ rb = xp + rp * W;
      const int sl = (iy + 2) % 3;               // compile-time
      ring[sl][0] = *reinterpret_cast<const vf4*>(rb + o0);
      ring[sl][1] = *reinterpret_cast<const vf4*>(rb + o1);
      ring[sl][2] = *reinterpret_cast<const vf4*>(rb + o2);
    }

    // ---- consume row iy (input row y0w-3+iy) from slot iy%3 ----
    const int r = y0w - 3 + iy;
    // pad possible only at compile-time edge iys -> interior is branch-free
    if ((iy >= 3 && iy <= 18) || (r >= 0 && r < H)) {
      const int cs = iy % 3;                     // compile-time
      vf4 q0 = ring[cs][0];                      // buf[0..3]
      vf4 q1 = ring[cs][1];                      // buf[4..7]
      vf4 q2 = ring[cs][2];                      // buf[8..11]

      // edge fixes: lane 0's cols -3..-1, lane 63's cols 256..258 -> -MAXV
      q0.y = l0 ? -MAXV : q0.y;
      q0.z = l0 ? -MAXV : q0.z;
      q0.w = l0 ? -MAXV : q0.w;
      q2.x = l63 ? -MAXV : q2.x;
      q2.y = l63 ? -MAXV : q2.y;
      q2.z = l63 ? -MAXV : q2.z;

      // odd-start pairs (2 movs each): (b1,b2)(b3,b4)(b5,b6)(b7,b8)
      const vf2 O0 = __builtin_shufflevector(q0, q0, 1, 2);
      const vf2 O1 = __builtin_shufflevector(q0, q1, 3, 4);
      const vf2 O2 = __builtin_shufflevector(q1, q1, 1, 2);
      const vf2 O3 = __builtin_shufflevector(q1, q2, 3, 4);
      // even-start pairs (free quad sub-pairs): (b2,b3)(b4,b5)(b6,b7)(b8,b9)
      const vf2 E0 = __builtin_shufflevector(q0, q0, 2, 3);
      const vf2 E1 = __builtin_shufflevector(q1, q1, 0, 1);
      const vf2 E2 = __builtin_shufflevector(q1, q1, 2, 3);
      const vf2 E3 = __builtin_shufflevector(q2, q2, 0, 1);

      const vf2 P[4][3] = {{O0, O1, O2}, {E0, E1, E2}, {O1, O2, O3}, {E1, E2, E3}};
      const float T[4] = {q1.w, q2.x, q2.y, q2.z};

      // contribute to all live outputs t = iy-dd, dd = weight row (dy+3)
#pragma unroll
      for (int dd = 0; dd < 7; ++dd) {
        const int t = iy - dd;
        if (t < 0 || t > 15) continue;           // compile-time dead
        const int st = t % 7;                    // compile-time
#pragma unroll
        for (int c = 0; c < 4; ++c) {
          const vf2 a = P[c][0] + wp[dd][0];     // v_pk_add_f32
          const vf2 b = P[c][1] + wp[dd][1];     // v_pk_add_f32
          const vf2 g = P[c][2] + wp[dd][2];     // v_pk_add_f32
          const float s6 = T[c] + w6[dd];
          const float m0 = fmaxf(fmaxf(a.x, a.y), b.x);   // v_max3
          const float m1 = fmaxf(fmaxf(b.y, g.x), g.y);   // v_max3
          const float m2 = fmaxf(fmaxf(s6, m0), m1);      // v_max3
          acc[st][c] = fmaxf(acc[st][c], m2);
        }
      }
    }

    // ---- retire output row t = iy-6 (slot (iy-6)%7), then re-init slot ----
    if (iy >= 6) {                               // compile-time
      const int tr = iy - 6;
      const int st = tr % 7;                     // compile-time
      vf4 v;
      v.x = acc[st][0];
      v.y = acc[st][1];
      v.z = acc[st][2];
      v.w = acc[st][3];
      __builtin_nontemporal_store(
          v, reinterpret_cast<vf4*>(&op[(y0w + tr) * W + o1]));
      if (iy <= 14) {                            // slot reused by t = iy+1
#pragma unroll
        for (int c = 0; c < 4; ++c) acc[st][c] = -INFINITY;
      }
    }
  }
}

extern "C" void kernel_launch(void* const* d_in, const int* in_sizes, int n_in,
                              void* d_out, int out_size, void* d_ws, size_t ws_size,
                              hipStream_t stream) {
  const float* x = (const float*)d_in[0];
  const float* k1 = (const float*)d_in[1];
  const float* k2 = (const float*)d_in[2];
  const float* k3 = (const float*)d_in[3];
  float* outp = (float*)d_out;

  const int planes = 8 * 64;                     // 512
  const int blocks = planes * 4;                 // 2048 (4 waves x 16 rows)
  morpho_kernel<<<dim3(blocks), dim3(256), 0, stream>>>(x, k1, k2, k3, outp);
}

// Round 8
// 247.731 us; speedup vs baseline: 1.0803x; 1.0068x over previous
//
#include <hip/hip_runtime.h>

// QuadraticBaseMorpho: out[h][w] = max_{dy,dx in [-3,3]} xpad[h+dy][w+dx] + nb[dy+3][dx+3]
// xpad = x padded with -10000. nb = -(se/se.max()) with center forced to -10000.
// se is even-symmetric -> the [::-1,::-1] flip is identity.
// Input (8,64,256,256) fp32 = 512 planes of 256x256.
//
// Round-8: r5's streaming sliding-window + the two levers that stop the
// scheduler from collapsing the prefetch ring. r4/r5 post-mortem (VGPR=52/56):
// __launch_bounds__(256,4) only sets a MINIMUM occupancy; the pre-RA
// scheduler still targets the best achievable tier (<=64 VGPR, 8 waves/EU)
// and deliberately sinks loads to uses to get there. Fix:
//   1) amdgpu_waves_per_eu(4,4): max==min==4 -> scheduler's occupancy target
//      is exactly 4 waves/EU (128-VGPR budget); no reward for squeezing.
//   2) __builtin_amdgcn_sched_barrier(0) after each prefetch block: hard
//      scheduling-region boundary, loads cannot migrate down to their uses.
// The compiler then emits its own counted s_waitcnt vmcnt(N) at each consume
// (straight-line code, all intervening loads statically known). No inline-asm
// waits, no global_load_lds, no LDS, no barriers -> this kernel cannot hang;
// if the container fails again it is proof of infra (rounds 6/7 never ran).
//
// Streaming map (r5, validated absmax=0): each wave owns 16 CONTIGUOUS output
// rows, streams its 22 input rows exactly once (66 loads/wave). Arriving row
// contributes to all live outputs (up to 7 weight-rows) then dies. Rotating
// 7-slot accumulators; store one finished row per step from iy=6. Prefetch:
// 3-slot register ring, depth 2, unconditional clamped-address loads (clamped
// garbage never consumed: pad steps skipped, skip branch only survives at
// compile-time edge iys). All %3/%7 indices compile-time (22-step unroll).
//
// Per (t,c,d): 3 v_pk_add_f32 + 1 add + 3 v_max3 + 1 max.

#define MAXV 10000.0f

constexpr int H = 256;
constexpr int W = 256;

typedef float vf4 __attribute__((ext_vector_type(4)));
typedef float vf2 __attribute__((ext_vector_type(2)));

__global__ __attribute__((amdgpu_flat_work_group_size(256, 256),
                          amdgpu_waves_per_eu(4, 4)))
void morpho_kernel(
    const float* __restrict__ x,
    const float* __restrict__ k1p,
    const float* __restrict__ k2p,
    const float* __restrict__ k3p,
    float* __restrict__ out) {
  const int tid = threadIdx.x;
  const int lane = tid & 63;
  const int wid = __builtin_amdgcn_readfirstlane(tid >> 6);  // wave id, uniform
  const int p = blockIdx.x >> 2;                 // plane (512)
  const int y0w = (blockIdx.x & 3) * 64 + wid * 16;  // wave's first output row

  const float* __restrict__ xp = x + (size_t)p * (H * W);
  float* __restrict__ op = out + (size_t)p * (H * W);

  // ---- SE: one weight per lane (8x8 grid), shuffle-max, readlane -> SGPRs ----
  const float k1v = k1p[0], k2v = k2p[0], k3v = k3p[0];
  const int ia = lane >> 3, ib = lane & 7;
  const float xg = (float)(((ib < 6) ? ib : 6) - 3);   // clamp dup lanes; max unaffected
  const float yg = (float)(((ia < 6) ? ia : 6) - 3);
  const float sev = k1v * (xg * xg) + 2.0f * k2v * (xg * yg) + k3v * (yg * yg);
  float mx = sev;
#pragma unroll
  for (int off = 32; off; off >>= 1) mx = fmaxf(mx, __shfl_xor(mx, off, 64));
  const float wv = 0.0f - sev * (1.0f / mx);

  // weight row d: pairs (w0,w1)(w2,w3)(w4,w5) + scalar w6 -> 49 SGPRs total
  vf2 wp[7][3];
  float w6[7];
#pragma unroll
  for (int d = 0; d < 7; ++d) {
#pragma unroll
    for (int m = 0; m < 3; ++m) {
      vf2 pr;
      pr.x = __int_as_float(__builtin_amdgcn_readlane(__float_as_int(wv), d * 8 + 2 * m));
      pr.y = __int_as_float(__builtin_amdgcn_readlane(__float_as_int(wv), d * 8 + 2 * m + 1));
      wp[d][m] = pr;
    }
    w6[d] = __int_as_float(__builtin_amdgcn_readlane(__float_as_int(wv), d * 8 + 6));
  }
  wp[3][1].y = -MAXV;                            // masked center (d=3, j=3)

  // ---- per-lane load offsets (float indices), clamped into the row ----
  const bool l0 = (lane == 0);
  const bool l63 = (lane == 63);
  const int o1 = lane * 4;                       // q1: cols lane*4 .. +3
  const int o0 = l0 ? o1 : o1 - 4;               // q0: cols lane*4-4 .. -1
  const int o2 = l63 ? o1 : o1 + 4;              // q2: cols lane*4+4 .. +7

  // ---- 3-slot prefetch ring (depth 2), unconditional clamped loads ----
  vf4 ring[3][3];
  {
    const int r0 = (y0w - 3 < 0) ? 0 : y0w - 3;  // step 0
    const float* __restrict__ rb = xp + r0 * W;
    ring[0][0] = *reinterpret_cast<const vf4*>(rb + o0);
    ring[0][1] = *reinterpret_cast<const vf4*>(rb + o1);
    ring[0][2] = *reinterpret_cast<const vf4*>(rb + o2);
  }
  {
    const int r1 = (y0w - 2 < 0) ? 0 : y0w - 2;  // step 1
    const float* __restrict__ rb = xp + r1 * W;
    ring[1][0] = *reinterpret_cast<const vf4*>(rb + o0);
    ring[1][1] = *reinterpret_cast<const vf4*>(rb + o1);
    ring[1][2] = *reinterpret_cast<const vf4*>(rb + o2);
  }
  __builtin_amdgcn_sched_barrier(0);             // pin prologue loads up here

  // ---- 7 rotating accumulator slots (slot = t % 7) ----
  float acc[7][4];
#pragma unroll
  for (int s = 0; s < 7; ++s)
#pragma unroll
    for (int c = 0; c < 4; ++c) acc[s][c] = -INFINITY;

#pragma unroll
  for (int iy = 0; iy < 22; ++iy) {              // input rows y0w-3 .. y0w+18
    // ---- prefetch row for step iy+2 into slot (iy+2)%3, then FENCE ----
    if (iy < 20) {                               // compile-time
      int rp = y0w - 1 + iy;                     // = y0w-3+(iy+2)
      rp = (rp < 0) ? 0 : ((rp > H - 1) ? H - 1 : rp);   // clamp, branchless
      const float* __restrict__ rb = xp + rp * W;
      const int sl = (iy + 2) % 3;               // compile-time
      ring[sl][0] = *reinterpret_cast<const vf4*>(rb + o0);
      ring[sl][1] = *reinterpret_cast<const vf4*>(rb + o1);
      ring[sl][2] = *reinterpret_cast<const vf4*>(rb + o2);
      __builtin_amdgcn_sched_barrier(0);         // loads may not sink past here
    }

    // ---- consume row iy (input row y0w-3+iy) from slot iy%3 ----
    const int r = y0w - 3 + iy;
    // pad possible only at compile-time edge iys -> interior is branch-free
    if ((iy >= 3 && iy <= 18) || (r >= 0 && r < H)) {
      const int cs = iy % 3;                     // compile-time
      vf4 q0 = ring[cs][0];                      // buf[0..3]
      vf4 q1 = ring[cs][1];                      // buf[4..7]
      vf4 q2 = ring[cs][2];                      // buf[8..11]

      // edge fixes: lane 0's cols -3..-1, lane 63's cols 256..258 -> -MAXV
      q0.y = l0 ? -MAXV : q0.y;
      q0.z = l0 ? -MAXV : q0.z;
      q0.w = l0 ? -MAXV : q0.w;
      q2.x = l63 ? -MAXV : q2.x;
      q2.y = l63 ? -MAXV : q2.y;
      q2.z = l63 ? -MAXV : q2.z;

      // odd-start pairs (2 movs each): (b1,b2)(b3,b4)(b5,b6)(b7,b8)
      const vf2 O0 = __builtin_shufflevector(q0, q0, 1, 2);
      const vf2 O1 = __builtin_shufflevector(q0, q1, 3, 4);
      const vf2 O2 = __builtin_shufflevector(q1, q1, 1, 2);
      const vf2 O3 = __builtin_shufflevector(q1, q2, 3, 4);
      // even-start pairs (free quad sub-pairs): (b2,b3)(b4,b5)(b6,b7)(b8,b9)
      const vf2 E0 = __builtin_shufflevector(q0, q0, 2, 3);
      const vf2 E1 = __builtin_shufflevector(q1, q1, 0, 1);
      const vf2 E2 = __builtin_shufflevector(q1, q1, 2, 3);
      const vf2 E3 = __builtin_shufflevector(q2, q2, 0, 1);

      const vf2 P[4][3] = {{O0, O1, O2}, {E0, E1, E2}, {O1, O2, O3}, {E1, E2, E3}};
      const float T[4] = {q1.w, q2.x, q2.y, q2.z};

      // contribute to all live outputs t = iy-dd, dd = weight row (dy+3)
#pragma unroll
      for (int dd = 0; dd < 7; ++dd) {
        const int t = iy - dd;
        if (t < 0 || t > 15) continue;           // compile-time dead
        const int st = t % 7;                    // compile-time
#pragma unroll
        for (int c = 0; c < 4; ++c) {
          const vf2 a = P[c][0] + wp[dd][0];     // v_pk_add_f32
          const vf2 b = P[c][1] + wp[dd][1];     // v_pk_add_f32
          const vf2 g = P[c][2] + wp[dd][2];     // v_pk_add_f32
          const float s6 = T[c] + w6[dd];
          const float m0 = fmaxf(fmaxf(a.x, a.y), b.x);   // v_max3
          const float m1 = fmaxf(fmaxf(b.y, g.x), g.y);   // v_max3
          const float m2 = fmaxf(fmaxf(s6, m0), m1);      // v_max3
          acc[st][c] = fmaxf(acc[st][c], m2);
        }
      }
    }

    // ---- retire output row t = iy-6 (slot (iy-6)%7), then re-init slot ----
    if (iy >= 6) {                               // compile-time
      const int tr = iy - 6;
      const int st = tr % 7;                     // compile-time
      vf4 v;
      v.x = acc[st][0];
      v.y = acc[st][1];
      v.z = acc[st][2];
      v.w = acc[st][3];
      __builtin_nontemporal_store(
          v, reinterpret_cast<vf4*>(&op[(y0w + tr) * W + o1]));
      if (iy <= 14) {                            // slot reused by t = iy+1
#pragma unroll
        for (int c = 0; c < 4; ++c) acc[st][c] = -INFINITY;
      }
    }
  }
}

extern "C" void kernel_launch(void* const* d_in, const int* in_sizes, int n_in,
                              void* d_out, int out_size, void* d_ws, size_t ws_size,
                              hipStream_t stream) {
  const float* x = (const float*)d_in[0];
  const float* k1 = (const float*)d_in[1];
  const float* k2 = (const float*)d_in[2];
  const float* k3 = (const float*)d_in[3];
  float* outp = (float*)d_out;

  const int planes = 8 * 64;                     // 512
  const int blocks = planes * 4;                 // 2048 (4 waves x 16 rows)
  morpho_kernel<<<dim3(blocks), dim3(256), 0, stream>>>(x, k1, k2, k3, outp);
}